// Round 4
// baseline (473.559 us; speedup 1.0000x reference)
//
#include <hip/hip_runtime.h>
#include <math.h>

typedef _Float16 half8 __attribute__((ext_vector_type(8)));
typedef float    f32x4 __attribute__((ext_vector_type(4)));

#define NROWS 16384
#define DIMS  512
#define KC    8192
#define DELTA 0.5f
#define CAP   262144

// sortable-key helpers: smaller float -> smaller unsigned
__device__ inline unsigned fkey(float v) {
    unsigned u = __float_as_uint(v);
    return (u & 0x80000000u) ? ~u : (u | 0x80000000u);
}
__device__ inline float unfkey(unsigned u) {
    return (u & 0x80000000u) ? __uint_as_float(u & 0x7FFFFFFFu)
                             : __uint_as_float(~u);
}
__device__ inline unsigned long long shflxor_u64(unsigned long long v, int m) {
    int lo = __shfl_xor((int)(unsigned)(v & 0xffffffffull), m, 64);
    int hi = __shfl_xor((int)(unsigned)(v >> 32), m, 64);
    return ((unsigned long long)(unsigned)hi << 32) | (unsigned)lo;
}

// ---------------------------------------------------------------------------
// K0: per-row sum of squares of embedding (fp64 accum, fp32 out).
// ---------------------------------------------------------------------------
__global__ __launch_bounds__(256)
void rowsq_kernel(const float* __restrict__ in, float* __restrict__ out, int nrows)
{
    int gtid = blockIdx.x * blockDim.x + threadIdx.x;
    int w = gtid >> 6;
    int lane = threadIdx.x & 63;
    if (w >= nrows) return;
    const float* r = in + (size_t)w * DIMS;
    float4 v0 = *(const float4*)(r + lane * 4);
    float4 v1 = *(const float4*)(r + 256 + lane * 4);
    double s = (double)v0.x * v0.x + (double)v0.y * v0.y +
               (double)v0.z * v0.z + (double)v0.w * v0.w +
               (double)v1.x * v1.x + (double)v1.y * v1.y +
               (double)v1.z * v1.z + (double)v1.w * v1.w;
    #pragma unroll
    for (int off = 32; off; off >>= 1) s += __shfl_down(s, off);
    if (lane == 0) out[w] = (float)s;
}

// ---------------------------------------------------------------------------
// K0b: convert fp32 rows -> fp16 in K-blocked panel layout.
// Panel = 256 rows. Layout (halfs): p*131072 + s*8192 + r*32 + g4*8
//   (s = K-step 0..15 of 32 floats; g4 = 8-elem group 0..3 within step)
// One block = (p, s, rq): 256 threads cover r = rq*64 + (t>>2), g4 = t&3.
// Writes are fully coalesced (4KB contiguous per block).
// ---------------------------------------------------------------------------
__global__ __launch_bounds__(256)
void cvt_kernel(const float* __restrict__ src, _Float16* __restrict__ dst)
{
    int b = blockIdx.x, t = threadIdx.x;
    int p = b >> 6, s = (b >> 2) & 15, rq = b & 3;
    int r = rq * 64 + (t >> 2), g4 = t & 3;
    int row = p * 256 + r;
    const float* sp = src + (size_t)row * DIMS + (s * 4 + g4) * 8;
    float4 v0 = *(const float4*)(sp + 0);
    float4 v1 = *(const float4*)(sp + 4);
    half8 h;
    h[0] = (_Float16)v0.x; h[1] = (_Float16)v0.y;
    h[2] = (_Float16)v0.z; h[3] = (_Float16)v0.w;
    h[4] = (_Float16)v1.x; h[5] = (_Float16)v1.y;
    h[6] = (_Float16)v1.z; h[7] = (_Float16)v1.w;
    *(half8*)(dst + (size_t)p * 131072 + s * 8192 + r * 32 + g4 * 8) = h;
}

// ---------------------------------------------------------------------------
// K1: fp16 screen GEMM + per-(row, 256-col-block) top-2 table.
// Block 256x256, 8 waves (2 row x 4 col) of 128x64 wave tiles, BK=32.
// Double-buffered LDS (2 x 32KB), global_load_lds staging (1KB chunks are
// verbatim copies of contiguous global chunks). Frag ds_read_b128s are a
// contiguous 1KB per wave -> zero bank conflicts.
// ---------------------------------------------------------------------------
__global__ __launch_bounds__(512, 2)
void screen_kernel(const char* __restrict__ zh, const char* __restrict__ eh,
                   const float* __restrict__ esf,
                   unsigned long long* __restrict__ tab)
{
    __shared__ char smem[65536];   // buf0: A 16K | B 16K ; buf1: A 16K | B 16K

    const int t    = threadIdx.x;
    const int lane = t & 63;
    const int wave = t >> 6;
    const int lg   = lane >> 4;
    const int lr   = lane & 15;
    const int wm   = wave >> 2;      // 0..1 (row half)
    const int wn   = wave & 3;       // 0..3 (col quarter)
    const int bx   = blockIdx.x;     // 0..63 row panel
    const int by   = blockIdx.y;     // 0..31 col panel

    const char* gA = zh + (size_t)bx * 262144;
    const char* gB = eh + (size_t)by * 262144;

    f32x4 acc[8][4];
    #pragma unroll
    for (int i = 0; i < 8; ++i)
        #pragma unroll
        for (int j = 0; j < 4; ++j)
            acc[i][j] = (f32x4){0.f, 0.f, 0.f, 0.f};

    // ---- staging: wave w issues 4 chunks (A for w<4, B for w>=4) ----
    typedef const __attribute__((address_space(1))) unsigned int gq_t;
    typedef __attribute__((address_space(3))) unsigned int lq_t;
    #define STAGE(buf, s)                                                     \
    {                                                                         \
        char* lbase = smem + (buf) * 32768 + (wave >= 4 ? 16384 : 0);         \
        const char* gbase = (wave >= 4 ? gB : gA) + (size_t)(s) * 16384;      \
        int c0 = (wave & 3) * 4;                                              \
        _Pragma("unroll")                                                     \
        for (int k = 0; k < 4; ++k) {                                         \
            __builtin_amdgcn_global_load_lds(                                 \
                (gq_t*)(gbase + (c0 + k) * 1024 + lane * 16),                 \
                (lq_t*)(lbase + (c0 + k) * 1024), 16, 0, 0);                  \
        }                                                                     \
    }

    STAGE(0, 0);
    __syncthreads();

    #pragma unroll 1
    for (int s = 0; s < 16; ++s) {
        if (s < 15) STAGE((s + 1) & 1, s + 1);

        const char* Ab = smem + (s & 1) * 32768;
        half8 af[8], bf[4];
        #pragma unroll
        for (int i = 0; i < 8; ++i)
            af[i] = *(const half8*)(Ab + ((wm * 128 + i * 16 + lr) * 4 + lg) * 16);
        #pragma unroll
        for (int j = 0; j < 4; ++j)
            bf[j] = *(const half8*)(Ab + 16384 + ((wn * 64 + j * 16 + lr) * 4 + lg) * 16);

        #pragma unroll
        for (int i = 0; i < 8; ++i)
            #pragma unroll
            for (int j = 0; j < 4; ++j)
                acc[i][j] = __builtin_amdgcn_mfma_f32_16x16x32_f16(
                    af[i], bf[j], acc[i][j], 0, 0, 0);

        __syncthreads();
    }

    // ---- epilogue: per-row top-2 within this block's 256 cols ----
    unsigned long long* mb = (unsigned long long*)smem;  // [256][4][4][2]
    float es_j[4];
    #pragma unroll
    for (int j = 0; j < 4; ++j)
        es_j[j] = esf[by * 256 + wn * 64 + j * 16 + lr];

    #pragma unroll
    for (int i = 0; i < 8; ++i) {
        #pragma unroll
        for (int r = 0; r < 4; ++r) {
            unsigned long long k1 = ~0ull, k2 = ~0ull;
            #pragma unroll
            for (int j = 0; j < 4; ++j) {
                float v = fmaf(-2.f, acc[i][j][r], es_j[j]);
                int col = by * 256 + wn * 64 + j * 16 + lr;
                unsigned long long k =
                    ((unsigned long long)fkey(v) << 32) | (unsigned)col;
                if (k < k1) { k2 = k1; k1 = k; }
                else if (k < k2) { k2 = k; }
            }
            #pragma unroll
            for (int m = 1; m <= 2; m <<= 1) {
                unsigned long long o1 = shflxor_u64(k1, m);
                unsigned long long o2 = shflxor_u64(k2, m);
                unsigned long long n1 = k1 < o1 ? k1 : o1;
                unsigned long long hi = k1 < o1 ? o1 : k1;
                unsigned long long l2 = k2 < o2 ? k2 : o2;
                k1 = n1;
                k2 = hi < l2 ? hi : l2;
            }
            if ((lr & 3) == 0) {
                int row = wm * 128 + i * 16 + lg * 4 + r;
                int idx = (row * 32 + wn * 8 + (lr >> 2) * 2);
                mb[idx + 0] = k1;
                mb[idx + 1] = k2;
            }
        }
    }
    __syncthreads();

    if (t < 256) {
        unsigned long long k1 = ~0ull, k2 = ~0ull;
        #pragma unroll 4
        for (int q = 0; q < 32; ++q) {
            unsigned long long k = mb[t * 32 + q];
            if (k < k1) { k2 = k1; k1 = k; }
            else if (k < k2) { k2 = k; }
        }
        size_t o = ((size_t)(bx * 256 + t) * 32 + by) * 2;
        tab[o + 0] = k1;
        tab[o + 1] = k2;
    }
}

// ---------------------------------------------------------------------------
// K2: collect candidates within DELTA of each row's approx min.
// One wave per row scans its 64 table entries (32 blocks x top-2).
// ---------------------------------------------------------------------------
__global__ __launch_bounds__(256)
void collect_kernel(const unsigned long long* __restrict__ tab,
                    unsigned* __restrict__ cand, int* __restrict__ ncand)
{
    int t = threadIdx.x, lane = t & 63;
    int row = blockIdx.x * 4 + (t >> 6);
    unsigned long long k = tab[(size_t)row * 64 + lane];
    unsigned long long m = k;
    #pragma unroll
    for (int mask = 1; mask <= 32; mask <<= 1) {
        unsigned long long o = shflxor_u64(m, mask);
        m = o < m ? o : m;
    }
    float vb = unfkey((unsigned)(m >> 32));
    unsigned uthr = fkey(vb + DELTA);
    if ((unsigned)(k >> 32) <= uthr) {
        int pos = atomicAdd(ncand, 1);
        if (pos < CAP)
            cand[pos] = ((unsigned)row << 13) | (unsigned)(k & 8191u);
    }
}

// ---------------------------------------------------------------------------
// K3: exact fp32 rescore of candidates -> atomicMin final row keys.
// ---------------------------------------------------------------------------
__global__ __launch_bounds__(256)
void rescore_kernel(const float* __restrict__ z, const float* __restrict__ emb,
                    const float* __restrict__ esf,
                    const unsigned* __restrict__ cand,
                    const int* __restrict__ ncand,
                    unsigned long long* __restrict__ rowkey)
{
    int n = *ncand; if (n > CAP) n = CAP;
    int wid = blockIdx.x * 4 + (threadIdx.x >> 6);
    int lane = threadIdx.x & 63;
    for (int c = wid; c < n; c += 4096) {
        unsigned pc = cand[c];
        int row = pc >> 13, col = pc & 8191;
        const float4* zr = (const float4*)(z + (size_t)row * DIMS + lane * 8);
        const float4* er = (const float4*)(emb + (size_t)col * DIMS + lane * 8);
        float4 a0 = zr[0], a1 = zr[1], b0 = er[0], b1 = er[1];
        float s = a0.x * b0.x;
        s = fmaf(a0.y, b0.y, s); s = fmaf(a0.z, b0.z, s);
        s = fmaf(a0.w, b0.w, s); s = fmaf(a1.x, b1.x, s);
        s = fmaf(a1.y, b1.y, s); s = fmaf(a1.z, b1.z, s);
        s = fmaf(a1.w, b1.w, s);
        #pragma unroll
        for (int mask = 32; mask; mask >>= 1) s += __shfl_xor(s, mask);
        if (lane == 0) {
            float v = fmaf(-2.f, s, esf[col]);
            unsigned long long key =
                ((unsigned long long)fkey(v) << 32) | (unsigned)col;
            atomicMin(rowkey + row, key);
        }
    }
}

// ---------------------------------------------------------------------------
// K4: decode per-row keys -> index output + histogram
// ---------------------------------------------------------------------------
__global__ __launch_bounds__(256)
void combine_kernel(const unsigned long long* __restrict__ rowkey,
                    float* __restrict__ out_idx_f, int* __restrict__ counts)
{
    int r = blockIdx.x * 256 + threadIdx.x;
    int idx = (int)(rowkey[r] & 0xFFFFFFFFull);
    out_idx_f[r] = (float)idx;
    atomicAdd(&counts[idx], 1);
}

// ---------------------------------------------------------------------------
// K5: gather quantized = embedding[idx], write out, partial (q-z)^2 sums
// ---------------------------------------------------------------------------
__global__ __launch_bounds__(256)
void gather_loss_kernel(const float* __restrict__ z, const float* __restrict__ emb,
                        const float* __restrict__ idxf, float* __restrict__ outq,
                        float* __restrict__ bsums)
{
    int gid = blockIdx.x * 256 + threadIdx.x;
    int row = gid >> 7;
    int c4  = (gid & 127) << 2;
    int idx = (int)idxf[row];
    float4 e  = *(const float4*)&emb[(size_t)idx * DIMS + c4];
    float4 zv = *(const float4*)&z[(size_t)row * DIMS + c4];
    *(float4*)&outq[(size_t)row * DIMS + c4] = e;
    float dx = e.x - zv.x, dy = e.y - zv.y, dz = e.z - zv.z, dw = e.w - zv.w;
    float s = dx * dx + dy * dy + dz * dz + dw * dw;
    #pragma unroll
    for (int off = 32; off; off >>= 1) s += __shfl_down(s, off);
    __shared__ float wsum[4];
    if ((threadIdx.x & 63) == 0) wsum[threadIdx.x >> 6] = s;
    __syncthreads();
    if (threadIdx.x == 0)
        bsums[blockIdx.x] = wsum[0] + wsum[1] + wsum[2] + wsum[3];
}

// ---------------------------------------------------------------------------
// K6: finalize scalars: vq_loss and perplexity
// ---------------------------------------------------------------------------
__global__ __launch_bounds__(256)
void finalize_kernel(const int* __restrict__ counts, const float* __restrict__ bsums,
                     float* __restrict__ out_scalars)
{
    int t = threadIdx.x;
    double ls = 0.0, ps = 0.0;
    for (int i = t; i < 8192; i += 256) {
        ls += (double)bsums[i];
        double avg = (double)counts[i] * (1.0 / 16384.0);
        ps += avg * log(avg + 1e-10);
    }
    #pragma unroll
    for (int off = 32; off; off >>= 1) {
        ls += __shfl_down(ls, off);
        ps += __shfl_down(ps, off);
    }
    __shared__ double l4[4], p4[4];
    if ((t & 63) == 0) { l4[t >> 6] = ls; p4[t >> 6] = ps; }
    __syncthreads();
    if (t == 0) {
        double L = l4[0] + l4[1] + l4[2] + l4[3];
        double P = p4[0] + p4[1] + p4[2] + p4[3];
        out_scalars[0] = (float)(1.25 * L / 8388608.0);
        out_scalars[1] = (float)exp(-P);
    }
}

// ---------------------------------------------------------------------------
// ws layout (bytes), total ~1.28 MB:
//   rowkey u64[16384] @ 0       (131072)  memset 0xFF
//   counts int[8192]  @ 131072  (32768)   memset 0
//   bsums  f32[8192]  @ 163840  (32768)
//   esf    f32[8192]  @ 196608  (32768)
//   ncand  int        @ 229376  (memset 0)
//   cand   u32[CAP]   @ 229632  (1048576)
// d_out scratch reuse (bytes) — consumed before gather overwrites:
//   zh16 @ 0         (16777216)   fp16 K-blocked z
//   eh16 @ 16777216  (8388608)    fp16 K-blocked emb
//   tab  @ 25165824  (8388608)    top-2 table [row][32][2] u64
// d_out final (floats): quantized[8388608] | vq_loss | perplexity | idx[16384]
// ---------------------------------------------------------------------------
extern "C" void kernel_launch(void* const* d_in, const int* in_sizes, int n_in,
                              void* d_out, int out_size, void* d_ws, size_t ws_size,
                              hipStream_t stream)
{
    const float* z   = (const float*)d_in[0];
    const float* emb = (const float*)d_in[1];

    float* out         = (float*)d_out;
    float* outq        = out;
    float* out_scalars = out + 8388608;
    float* out_idx     = out + 8388610;

    char* ob = (char*)d_out;
    _Float16* zh16 = (_Float16*)(ob + 0);
    _Float16* eh16 = (_Float16*)(ob + 16777216);
    unsigned long long* tab = (unsigned long long*)(ob + 25165824);

    char* ws = (char*)d_ws;
    unsigned long long* rowkey = (unsigned long long*)(ws + 0);
    int*      counts = (int*)     (ws + 131072);
    float*    bsums  = (float*)   (ws + 163840);
    float*    esf    = (float*)   (ws + 196608);
    int*      ncand  = (int*)     (ws + 229376);
    unsigned* cand   = (unsigned*)(ws + 229632);

    hipMemsetAsync(rowkey, 0xFF, NROWS * sizeof(unsigned long long), stream);
    hipMemsetAsync(counts, 0, KC * sizeof(int), stream);
    hipMemsetAsync(ncand, 0, sizeof(int), stream);

    rowsq_kernel<<<2048, 256, 0, stream>>>(emb, esf, KC);
    cvt_kernel<<<4096, 256, 0, stream>>>(z, zh16);     // 64 panels
    cvt_kernel<<<2048, 256, 0, stream>>>(emb, eh16);   // 32 panels
    screen_kernel<<<dim3(64, 32), 512, 0, stream>>>((const char*)zh16,
                                                    (const char*)eh16, esf, tab);
    collect_kernel<<<4096, 256, 0, stream>>>(tab, cand, ncand);
    rescore_kernel<<<1024, 256, 0, stream>>>(z, emb, esf, cand, ncand, rowkey);
    combine_kernel<<<NROWS / 256, 256, 0, stream>>>(rowkey, out_idx, counts);
    gather_loss_kernel<<<8192, 256, 0, stream>>>(z, emb, out_idx, outq, bsums);
    finalize_kernel<<<1, 256, 0, stream>>>(counts, bsums, out_scalars);
}

// Round 5
// 467.890 us; speedup vs baseline: 1.0121x; 1.0121x over previous
//
#include <hip/hip_runtime.h>
#include <math.h>

typedef _Float16 half8 __attribute__((ext_vector_type(8)));
typedef float    f32x4 __attribute__((ext_vector_type(4)));

#define NROWS 16384
#define DIMS  512
#define KC    8192
#define DELTA 0.5f
#define CAP   262144

// sortable-key helpers: smaller float -> smaller unsigned
__device__ inline unsigned fkey(float v) {
    unsigned u = __float_as_uint(v);
    return (u & 0x80000000u) ? ~u : (u | 0x80000000u);
}
__device__ inline float unfkey(unsigned u) {
    return (u & 0x80000000u) ? __uint_as_float(u & 0x7FFFFFFFu)
                             : __uint_as_float(~u);
}
__device__ inline unsigned long long shflxor_u64(unsigned long long v, int m) {
    int lo = __shfl_xor((int)(unsigned)(v & 0xffffffffull), m, 64);
    int hi = __shfl_xor((int)(unsigned)(v >> 32), m, 64);
    return ((unsigned long long)(unsigned)hi << 32) | (unsigned)lo;
}

// ---------------------------------------------------------------------------
// K0: per-row sum of squares of embedding (fp64 accum, fp32 out).
// ---------------------------------------------------------------------------
__global__ __launch_bounds__(256)
void rowsq_kernel(const float* __restrict__ in, float* __restrict__ out, int nrows)
{
    int gtid = blockIdx.x * blockDim.x + threadIdx.x;
    int w = gtid >> 6;
    int lane = threadIdx.x & 63;
    if (w >= nrows) return;
    const float* r = in + (size_t)w * DIMS;
    float4 v0 = *(const float4*)(r + lane * 4);
    float4 v1 = *(const float4*)(r + 256 + lane * 4);
    double s = (double)v0.x * v0.x + (double)v0.y * v0.y +
               (double)v0.z * v0.z + (double)v0.w * v0.w +
               (double)v1.x * v1.x + (double)v1.y * v1.y +
               (double)v1.z * v1.z + (double)v1.w * v1.w;
    #pragma unroll
    for (int off = 32; off; off >>= 1) s += __shfl_down(s, off);
    if (lane == 0) out[w] = (float)s;
}

// ---------------------------------------------------------------------------
// K0b: convert fp32 -> fp16 packed panels, fragment-chunk layout.
// Panel = 256 rows. Byte layout:
//   p*262144 + s*16384 + f*1024 + lg*256 + rr*16
// where s = K-step (32 floats), f = 16-row fragment (0..15), lg = 8-half
// k-group (0..3), rr = row-in-fragment (0..15).
// A fragment chunk (1KB) read at `chunk + lane*16` gives lane (lg=lane>>4,
// rr=lane&15) -> operand layout row=lane&15, kgrp=lane>>4. Lane-linear =>
// zero bank conflicts. Writes: 4KB contiguous per 256 threads.
// ---------------------------------------------------------------------------
__global__ __launch_bounds__(256)
void cvt_kernel(const float* __restrict__ src, _Float16* __restrict__ dst)
{
    int b = blockIdx.x, t = threadIdx.x;
    int p = b >> 4, s = b & 15;
    _Float16* dbase = dst + (size_t)p * 131072 + s * 8192;   // halfs
    #pragma unroll
    for (int q = 0; q < 4; ++q) {
        int c = q * 256 + t;                 // chunk 0..1023 (16B each)
        int f = c >> 6, lg = (c >> 4) & 3, rr = c & 15;
        int row = p * 256 + f * 16 + rr;
        const float* sp = src + (size_t)row * DIMS + s * 32 + lg * 8;
        float4 v0 = *(const float4*)(sp + 0);
        float4 v1 = *(const float4*)(sp + 4);
        half8 h;
        h[0] = (_Float16)v0.x; h[1] = (_Float16)v0.y;
        h[2] = (_Float16)v0.z; h[3] = (_Float16)v0.w;
        h[4] = (_Float16)v1.x; h[5] = (_Float16)v1.y;
        h[6] = (_Float16)v1.z; h[7] = (_Float16)v1.w;
        *(half8*)(dbase + c * 8) = h;
    }
}

// ---------------------------------------------------------------------------
// K1: fp16 screen GEMM + per-(row, 256-col-block) top-2 table.
// 256x256 block, 8 waves (2Mx4N) of 128x64, BK=32.
// 3-buffer rotation + counted vmcnt (T3/T4): STAGE(s+2) issued post-barrier,
// wait vmcnt(4) (never 0 until drain). Raw s_barrier (no compiler vmcnt(0)).
// Safety: buffer staged at iter s was last read at iter s-1; all waves
// completed those reads (lgkm-drained before their MFMAs) before reaching
// barrier(s), and STAGE issues after barrier(s).
// Fragment reads are lane-linear (chunk + lane*16): conflict-free.
// ---------------------------------------------------------------------------
__global__ __launch_bounds__(512, 1)
void screen_kernel(const char* __restrict__ zh, const char* __restrict__ eh,
                   const float* __restrict__ esf,
                   unsigned long long* __restrict__ tab)
{
    __shared__ char smem[98304];   // 3 x (A 16K | B 16K)

    const int t    = threadIdx.x;
    const int lane = t & 63;
    const int wave = t >> 6;
    const int lg   = lane >> 4;
    const int lr   = lane & 15;
    const int wm   = wave >> 2;      // 0..1 (row half)
    const int wn   = wave & 3;       // 0..3 (col quarter)
    const int bx   = blockIdx.x;     // row panel
    const int by   = blockIdx.y;     // col panel

    const char* gA = zh + (size_t)bx * 262144;
    const char* gB = eh + (size_t)by * 262144;

    f32x4 acc[8][4];
    #pragma unroll
    for (int i = 0; i < 8; ++i)
        #pragma unroll
        for (int j = 0; j < 4; ++j)
            acc[i][j] = (f32x4){0.f, 0.f, 0.f, 0.f};

    typedef const __attribute__((address_space(1))) unsigned int gq_t;
    typedef __attribute__((address_space(3))) unsigned int lq_t;
    #define STAGE(dstbuf, s)                                                  \
    {                                                                         \
        char* lb = (dstbuf) + (wave >= 4 ? 16384 : 0);                        \
        const char* gb = (wave >= 4 ? gB : gA) + (size_t)(s) * 16384;         \
        int c0 = (wave & 3) * 4;                                              \
        _Pragma("unroll")                                                     \
        for (int k = 0; k < 4; ++k) {                                         \
            __builtin_amdgcn_global_load_lds(                                 \
                (gq_t*)(gb + (c0 + k) * 1024 + lane * 16),                    \
                (lq_t*)(lb + (c0 + k) * 1024), 16, 0, 0);                     \
        }                                                                     \
    }

    char* p0 = smem;
    char* p1 = smem + 32768;
    char* p2 = smem + 65536;
    STAGE(p0, 0);
    STAGE(p1, 1);

    #pragma unroll 1
    for (int s = 0; s < 16; ++s) {
        if (s < 15) asm volatile("s_waitcnt vmcnt(4)" ::: "memory");
        else        asm volatile("s_waitcnt vmcnt(0)" ::: "memory");
        __builtin_amdgcn_s_barrier();

        const char* Ab = p0 + (wm * 8) * 1024 + lane * 16;
        const char* Bb = p0 + 16384 + (wn * 4) * 1024 + lane * 16;
        half8 af[8], bf[4];
        #pragma unroll
        for (int i = 0; i < 8; ++i) af[i] = *(const half8*)(Ab + i * 1024);
        #pragma unroll
        for (int j = 0; j < 4; ++j) bf[j] = *(const half8*)(Bb + j * 1024);

        if (s < 14) STAGE(p2, s + 2);

        __builtin_amdgcn_s_setprio(1);
        #pragma unroll
        for (int i = 0; i < 8; ++i)
            #pragma unroll
            for (int j = 0; j < 4; ++j)
                acc[i][j] = __builtin_amdgcn_mfma_f32_16x16x32_f16(
                    af[i], bf[j], acc[i][j], 0, 0, 0);
        __builtin_amdgcn_s_setprio(0);

        char* tmp = p0; p0 = p1; p1 = p2; p2 = tmp;
    }

    // ---- epilogue: per-row top-2 within this block's 256 cols ----
    __syncthreads();
    unsigned long long* mb = (unsigned long long*)smem;  // [256][4][4][2] 64KB
    float es_j[4];
    #pragma unroll
    for (int j = 0; j < 4; ++j)
        es_j[j] = esf[by * 256 + wn * 64 + j * 16 + lr];

    #pragma unroll
    for (int i = 0; i < 8; ++i) {
        #pragma unroll
        for (int r = 0; r < 4; ++r) {
            unsigned long long k1 = ~0ull, k2 = ~0ull;
            #pragma unroll
            for (int j = 0; j < 4; ++j) {
                float v = fmaf(-2.f, acc[i][j][r], es_j[j]);
                int col = by * 256 + wn * 64 + j * 16 + lr;
                unsigned long long k =
                    ((unsigned long long)fkey(v) << 32) | (unsigned)col;
                if (k < k1) { k2 = k1; k1 = k; }
                else if (k < k2) { k2 = k; }
            }
            #pragma unroll
            for (int m = 1; m <= 2; m <<= 1) {
                unsigned long long o1 = shflxor_u64(k1, m);
                unsigned long long o2 = shflxor_u64(k2, m);
                unsigned long long n1 = k1 < o1 ? k1 : o1;
                unsigned long long hi = k1 < o1 ? o1 : k1;
                unsigned long long l2 = k2 < o2 ? k2 : o2;
                k1 = n1;
                k2 = hi < l2 ? hi : l2;
            }
            if ((lr & 3) == 0) {
                int row = wm * 128 + i * 16 + lg * 4 + r;
                int idx = (row * 32 + wn * 8 + (lr >> 2) * 2);
                mb[idx + 0] = k1;
                mb[idx + 1] = k2;
            }
        }
    }
    __syncthreads();

    if (t < 256) {
        unsigned long long k1 = ~0ull, k2 = ~0ull;
        #pragma unroll 4
        for (int q = 0; q < 32; ++q) {
            unsigned long long k = mb[t * 32 + q];
            if (k < k1) { k2 = k1; k1 = k; }
            else if (k < k2) { k2 = k; }
        }
        size_t o = ((size_t)(bx * 256 + t) * 32 + by) * 2;
        tab[o + 0] = k1;
        tab[o + 1] = k2;
    }
}

// ---------------------------------------------------------------------------
// K2: collect candidates within DELTA of each row's approx min.
// ---------------------------------------------------------------------------
__global__ __launch_bounds__(256)
void collect_kernel(const unsigned long long* __restrict__ tab,
                    unsigned* __restrict__ cand, int* __restrict__ ncand)
{
    int t = threadIdx.x, lane = t & 63;
    int row = blockIdx.x * 4 + (t >> 6);
    unsigned long long k = tab[(size_t)row * 64 + lane];
    unsigned long long m = k;
    #pragma unroll
    for (int mask = 1; mask <= 32; mask <<= 1) {
        unsigned long long o = shflxor_u64(m, mask);
        m = o < m ? o : m;
    }
    float vb = unfkey((unsigned)(m >> 32));
    unsigned uthr = fkey(vb + DELTA);
    if ((unsigned)(k >> 32) <= uthr) {
        int pos = atomicAdd(ncand, 1);
        if (pos < CAP)
            cand[pos] = ((unsigned)row << 13) | (unsigned)(k & 8191u);
    }
}

// ---------------------------------------------------------------------------
// K3: exact fp32 rescore of candidates -> atomicMin final row keys.
// ---------------------------------------------------------------------------
__global__ __launch_bounds__(256)
void rescore_kernel(const float* __restrict__ z, const float* __restrict__ emb,
                    const float* __restrict__ esf,
                    const unsigned* __restrict__ cand,
                    const int* __restrict__ ncand,
                    unsigned long long* __restrict__ rowkey)
{
    int n = *ncand; if (n > CAP) n = CAP;
    int wid = blockIdx.x * 4 + (threadIdx.x >> 6);
    int lane = threadIdx.x & 63;
    for (int c = wid; c < n; c += 4096) {
        unsigned pc = cand[c];
        int row = pc >> 13, col = pc & 8191;
        const float4* zr = (const float4*)(z + (size_t)row * DIMS + lane * 8);
        const float4* er = (const float4*)(emb + (size_t)col * DIMS + lane * 8);
        float4 a0 = zr[0], a1 = zr[1], b0 = er[0], b1 = er[1];
        float s = a0.x * b0.x;
        s = fmaf(a0.y, b0.y, s); s = fmaf(a0.z, b0.z, s);
        s = fmaf(a0.w, b0.w, s); s = fmaf(a1.x, b1.x, s);
        s = fmaf(a1.y, b1.y, s); s = fmaf(a1.z, b1.z, s);
        s = fmaf(a1.w, b1.w, s);
        #pragma unroll
        for (int mask = 32; mask; mask >>= 1) s += __shfl_xor(s, mask);
        if (lane == 0) {
            float v = fmaf(-2.f, s, esf[col]);
            unsigned long long key =
                ((unsigned long long)fkey(v) << 32) | (unsigned)col;
            atomicMin(rowkey + row, key);
        }
    }
}

// ---------------------------------------------------------------------------
// K4: gather + loss partials + index output + histogram (combine fused in).
// ---------------------------------------------------------------------------
__global__ __launch_bounds__(256)
void gather_loss_kernel(const float* __restrict__ z, const float* __restrict__ emb,
                        const unsigned long long* __restrict__ rowkey,
                        float* __restrict__ outq, float* __restrict__ out_idx_f,
                        int* __restrict__ counts, float* __restrict__ bsums)
{
    int gid = blockIdx.x * 256 + threadIdx.x;
    int row = gid >> 7;
    int c4  = (gid & 127) << 2;
    int idx = (int)(rowkey[row] & 0xFFFFFFFFull);
    if ((gid & 127) == 0) {
        out_idx_f[row] = (float)idx;
        atomicAdd(&counts[idx], 1);
    }
    float4 e  = *(const float4*)&emb[(size_t)idx * DIMS + c4];
    float4 zv = *(const float4*)&z[(size_t)row * DIMS + c4];
    *(float4*)&outq[(size_t)row * DIMS + c4] = e;
    float dx = e.x - zv.x, dy = e.y - zv.y, dz = e.z - zv.z, dw = e.w - zv.w;
    float s = dx * dx + dy * dy + dz * dz + dw * dw;
    #pragma unroll
    for (int off = 32; off; off >>= 1) s += __shfl_down(s, off);
    __shared__ float wsum[4];
    if ((threadIdx.x & 63) == 0) wsum[threadIdx.x >> 6] = s;
    __syncthreads();
    if (threadIdx.x == 0)
        bsums[blockIdx.x] = wsum[0] + wsum[1] + wsum[2] + wsum[3];
}

// ---------------------------------------------------------------------------
// K5: finalize scalars: vq_loss and perplexity
// ---------------------------------------------------------------------------
__global__ __launch_bounds__(256)
void finalize_kernel(const int* __restrict__ counts, const float* __restrict__ bsums,
                     float* __restrict__ out_scalars)
{
    int t = threadIdx.x;
    double ls = 0.0, ps = 0.0;
    for (int i = t; i < 8192; i += 256) {
        ls += (double)bsums[i];
        double avg = (double)counts[i] * (1.0 / 16384.0);
        ps += avg * log(avg + 1e-10);
    }
    #pragma unroll
    for (int off = 32; off; off >>= 1) {
        ls += __shfl_down(ls, off);
        ps += __shfl_down(ps, off);
    }
    __shared__ double l4[4], p4[4];
    if ((t & 63) == 0) { l4[t >> 6] = ls; p4[t >> 6] = ps; }
    __syncthreads();
    if (t == 0) {
        double L = l4[0] + l4[1] + l4[2] + l4[3];
        double P = p4[0] + p4[1] + p4[2] + p4[3];
        out_scalars[0] = (float)(1.25 * L / 8388608.0);
        out_scalars[1] = (float)exp(-P);
    }
}

// ---------------------------------------------------------------------------
// ws layout (bytes):
//   rowkey u64[16384] @ 0       (131072)  memset 0xFF
//   counts int[8192]  @ 131072  (32768)   \ one memset 0 (32772 B)
//   ncand  int        @ 163840  (4)       /
//   bsums  f32[8192]  @ 164096  (32768)
//   esf    f32[8192]  @ 196864  (32768)
//   cand   u32[CAP]   @ 229632  (1048576)
// d_out scratch reuse (consumed before gather overwrites):
//   zh16 @ 0 (16MB) | eh16 @ 16777216 (8MB) | tab @ 25165824 (8MB)
// d_out final (floats): quantized[8388608] | vq_loss | perplexity | idx[16384]
// ---------------------------------------------------------------------------
extern "C" void kernel_launch(void* const* d_in, const int* in_sizes, int n_in,
                              void* d_out, int out_size, void* d_ws, size_t ws_size,
                              hipStream_t stream)
{
    const float* z   = (const float*)d_in[0];
    const float* emb = (const float*)d_in[1];

    float* out         = (float*)d_out;
    float* outq        = out;
    float* out_scalars = out + 8388608;
    float* out_idx     = out + 8388610;

    char* ob = (char*)d_out;
    _Float16* zh16 = (_Float16*)(ob + 0);
    _Float16* eh16 = (_Float16*)(ob + 16777216);
    unsigned long long* tab = (unsigned long long*)(ob + 25165824);

    char* ws = (char*)d_ws;
    unsigned long long* rowkey = (unsigned long long*)(ws + 0);
    int*      counts = (int*)     (ws + 131072);
    int*      ncand  = (int*)     (ws + 163840);
    float*    bsums  = (float*)   (ws + 164096);
    float*    esf    = (float*)   (ws + 196864);
    unsigned* cand   = (unsigned*)(ws + 229632);

    hipMemsetAsync(rowkey, 0xFF, 131072, stream);
    hipMemsetAsync(counts, 0, 32772, stream);

    rowsq_kernel<<<2048, 256, 0, stream>>>(emb, esf, KC);
    cvt_kernel<<<1024, 256, 0, stream>>>(z, zh16);     // 64 panels x 16 steps
    cvt_kernel<<<512, 256, 0, stream>>>(emb, eh16);    // 32 panels x 16 steps
    screen_kernel<<<dim3(64, 32), 512, 0, stream>>>((const char*)zh16,
                                                    (const char*)eh16, esf, tab);
    collect_kernel<<<4096, 256, 0, stream>>>(tab, cand, ncand);
    rescore_kernel<<<1024, 256, 0, stream>>>(z, emb, esf, cand, ncand, rowkey);
    gather_loss_kernel<<<8192, 256, 0, stream>>>(z, emb, rowkey, outq, out_idx,
                                                 counts, bsums);
    finalize_kernel<<<1, 256, 0, stream>>>(counts, bsums, out_scalars);
}

// Round 6
// 458.907 us; speedup vs baseline: 1.0319x; 1.0196x over previous
//
#include <hip/hip_runtime.h>
#include <math.h>

typedef _Float16 half8 __attribute__((ext_vector_type(8)));
typedef float    f32x4 __attribute__((ext_vector_type(4)));

#define NROWS 16384
#define DIMS  512
#define KC    8192
#define DELTA 0.5f
#define CAP   262144

// sortable-key helpers: smaller float -> smaller unsigned
__device__ inline unsigned fkey(float v) {
    unsigned u = __float_as_uint(v);
    return (u & 0x80000000u) ? ~u : (u | 0x80000000u);
}
__device__ inline float unfkey(unsigned u) {
    return (u & 0x80000000u) ? __uint_as_float(u & 0x7FFFFFFFu)
                             : __uint_as_float(~u);
}
__device__ inline unsigned long long shflxor_u64(unsigned long long v, int m) {
    int lo = __shfl_xor((int)(unsigned)(v & 0xffffffffull), m, 64);
    int hi = __shfl_xor((int)(unsigned)(v >> 32), m, 64);
    return ((unsigned long long)(unsigned)hi << 32) | (unsigned)lo;
}

// ---------------------------------------------------------------------------
// K0: fused prep. blocks [0,1024): cvt z panels; [1024,1536): cvt emb panels;
// [1536,3584): emb row sum-of-squares (fp64 accum); block 0 also zeroes ncand.
// cvt packed layout (halfs): p*131072 + s*8192 + c*8 where chunk unit
// c = f*64 + lg*16 + rr  (f = 16-row fragment, lg = 8-half k-group, rr = row).
// A 1KB fragment chunk read at +lane*16 gives lane -> (lg=lane>>4, rr=lane&15).
// ---------------------------------------------------------------------------
__global__ __launch_bounds__(256)
void prep_kernel(const float* __restrict__ z, const float* __restrict__ emb,
                 _Float16* __restrict__ zh16, _Float16* __restrict__ eh16,
                 float* __restrict__ esf, int* __restrict__ ncand)
{
    int b = blockIdx.x, t = threadIdx.x;
    if (b == 0 && t == 0) *ncand = 0;
    if (b < 1536) {
        const float* src;
        _Float16* dst;
        int pb;
        if (b < 1024) { src = z;   dst = zh16; pb = b; }
        else          { src = emb; dst = eh16; pb = b - 1024; }
        int p = pb >> 4, s = pb & 15;
        _Float16* dbase = dst + (size_t)p * 131072 + s * 8192;
        #pragma unroll
        for (int q = 0; q < 4; ++q) {
            int c = q * 256 + t;
            int f = c >> 6, lg = (c >> 4) & 3, rr = c & 15;
            int row = p * 256 + f * 16 + rr;
            const float* sp = src + (size_t)row * DIMS + s * 32 + lg * 8;
            float4 v0 = *(const float4*)(sp + 0);
            float4 v1 = *(const float4*)(sp + 4);
            half8 h;
            h[0] = (_Float16)v0.x; h[1] = (_Float16)v0.y;
            h[2] = (_Float16)v0.z; h[3] = (_Float16)v0.w;
            h[4] = (_Float16)v1.x; h[5] = (_Float16)v1.y;
            h[6] = (_Float16)v1.z; h[7] = (_Float16)v1.w;
            *(half8*)(dbase + c * 8) = h;
        }
    } else {
        int b2 = b - 1536;
        int w = b2 * 4 + (t >> 6);          // emb row 0..8191
        int lane = t & 63;
        const float* r = emb + (size_t)w * DIMS;
        float4 v0 = *(const float4*)(r + lane * 4);
        float4 v1 = *(const float4*)(r + 256 + lane * 4);
        double s = (double)v0.x * v0.x + (double)v0.y * v0.y +
                   (double)v0.z * v0.z + (double)v0.w * v0.w +
                   (double)v1.x * v1.x + (double)v1.y * v1.y +
                   (double)v1.z * v1.z + (double)v1.w * v1.w;
        #pragma unroll
        for (int off = 32; off; off >>= 1) s += __shfl_down(s, off);
        if (lane == 0) esf[w] = (float)s;
    }
}

// ---------------------------------------------------------------------------
// K1: fp16 screen GEMM + per-(row, 256-col-block) top-2 table.
// 256x256 block, 8 waves (2Mx4N) of 128x64, BK=32, 3 buffers, depth-2
// prefetch, ONE vmcnt(4) per K-step (per-wave FIFO: forces tile-s chunks
// landed while tile-s+1's 4 stay in flight).
// NEW (R6): 4-phase interleave per K-step. Each phase: {ds_read quadrant
// fragments; 1 stage chunk; s_barrier; lgkmcnt(0); setprio(1); 8 MFMA;
// setprio(0)}. Reads are issued pre-barrier and drain under the SIMD-mates'
// MFMA clusters -> LDS pipe and MFMA pipe overlap instead of alternating.
// Correctness: staged buffer (p2) never read this iteration; iter-top
// barrier separates last iter's p0 reads from staging into it; all branch
// conditions wave-uniform.
// ---------------------------------------------------------------------------
__global__ __launch_bounds__(512, 1)
void screen_kernel(const char* __restrict__ zh, const char* __restrict__ eh,
                   const float* __restrict__ esf,
                   unsigned long long* __restrict__ tab)
{
    __shared__ char smem[98304];   // 3 x (A 16K | B 16K)

    const int t    = threadIdx.x;
    const int lane = t & 63;
    const int wave = t >> 6;
    const int lg   = lane >> 4;
    const int lr   = lane & 15;
    const int wm   = wave >> 2;      // 0..1 (row half)
    const int wn   = wave & 3;       // 0..3 (col quarter)
    const int bx   = blockIdx.x;     // row panel
    const int by   = blockIdx.y;     // col panel

    const char* gA = zh + (size_t)bx * 262144;
    const char* gB = eh + (size_t)by * 262144;

    f32x4 acc[8][4];
    #pragma unroll
    for (int i = 0; i < 8; ++i)
        #pragma unroll
        for (int j = 0; j < 4; ++j)
            acc[i][j] = (f32x4){0.f, 0.f, 0.f, 0.f};

    typedef const __attribute__((address_space(1))) unsigned int gq_t;
    typedef __attribute__((address_space(3))) unsigned int lq_t;
    // stage one 1KB chunk (k = 0..3) of K-step s into dstbuf
    #define STAGE1(dstbuf, s, k)                                              \
    {                                                                         \
        int c = (wave & 3) * 4 + (k);                                         \
        char* lb = (dstbuf) + (wave >= 4 ? 16384 : 0) + c * 1024;             \
        const char* gb = (wave >= 4 ? gB : gA) + (size_t)(s) * 16384 + c * 1024; \
        __builtin_amdgcn_global_load_lds((gq_t*)(gb + lane * 16),             \
                                         (lq_t*)lb, 16, 0, 0);                \
    }
    #define MM(ii, jj)                                                        \
        acc[ii][jj] = __builtin_amdgcn_mfma_f32_16x16x32_f16(                 \
            af[ii], bf[jj], acc[ii][jj], 0, 0, 0)

    char* p0 = smem;
    char* p1 = smem + 32768;
    char* p2 = smem + 65536;
    STAGE1(p0, 0, 0); STAGE1(p0, 0, 1); STAGE1(p0, 0, 2); STAGE1(p0, 0, 3);
    STAGE1(p1, 1, 0); STAGE1(p1, 1, 1); STAGE1(p1, 1, 2); STAGE1(p1, 1, 3);

    #pragma unroll 1
    for (int s = 0; s < 16; ++s) {
        if (s < 15) asm volatile("s_waitcnt vmcnt(4)" ::: "memory");
        else        asm volatile("s_waitcnt vmcnt(0)" ::: "memory");
        __builtin_amdgcn_s_barrier();

        const char* Ab = p0 + (wm * 8) * 1024 + lane * 16;
        const char* Bb = p0 + 16384 + (wn * 4) * 1024 + lane * 16;
        half8 af[8], bf[4];

        // ---- phase 1: quadrant (i0-3, j0-1) ----
        af[0] = *(const half8*)(Ab + 0 * 1024);
        af[1] = *(const half8*)(Ab + 1 * 1024);
        af[2] = *(const half8*)(Ab + 2 * 1024);
        af[3] = *(const half8*)(Ab + 3 * 1024);
        bf[0] = *(const half8*)(Bb + 0 * 1024);
        bf[1] = *(const half8*)(Bb + 1 * 1024);
        if (s < 14) STAGE1(p2, s + 2, 0);
        __builtin_amdgcn_s_barrier();
        asm volatile("s_waitcnt lgkmcnt(0)" ::: "memory");
        __builtin_amdgcn_s_setprio(1);
        MM(0, 0); MM(0, 1); MM(1, 0); MM(1, 1);
        MM(2, 0); MM(2, 1); MM(3, 0); MM(3, 1);
        __builtin_amdgcn_s_setprio(0);

        // ---- phase 2: quadrant (i4-7, j0-1) ----
        af[4] = *(const half8*)(Ab + 4 * 1024);
        af[5] = *(const half8*)(Ab + 5 * 1024);
        af[6] = *(const half8*)(Ab + 6 * 1024);
        af[7] = *(const half8*)(Ab + 7 * 1024);
        if (s < 14) STAGE1(p2, s + 2, 1);
        __builtin_amdgcn_s_barrier();
        asm volatile("s_waitcnt lgkmcnt(0)" ::: "memory");
        __builtin_amdgcn_s_setprio(1);
        MM(4, 0); MM(4, 1); MM(5, 0); MM(5, 1);
        MM(6, 0); MM(6, 1); MM(7, 0); MM(7, 1);
        __builtin_amdgcn_s_setprio(0);

        // ---- phase 3: quadrant (i0-3, j2-3) ----
        bf[2] = *(const half8*)(Bb + 2 * 1024);
        bf[3] = *(const half8*)(Bb + 3 * 1024);
        if (s < 14) STAGE1(p2, s + 2, 2);
        __builtin_amdgcn_s_barrier();
        asm volatile("s_waitcnt lgkmcnt(0)" ::: "memory");
        __builtin_amdgcn_s_setprio(1);
        MM(0, 2); MM(0, 3); MM(1, 2); MM(1, 3);
        MM(2, 2); MM(2, 3); MM(3, 2); MM(3, 3);
        __builtin_amdgcn_s_setprio(0);

        // ---- phase 4: quadrant (i4-7, j2-3) ----
        if (s < 14) STAGE1(p2, s + 2, 3);
        __builtin_amdgcn_s_setprio(1);
        MM(4, 2); MM(4, 3); MM(5, 2); MM(5, 3);
        MM(6, 2); MM(6, 3); MM(7, 2); MM(7, 3);
        __builtin_amdgcn_s_setprio(0);

        char* tmp = p0; p0 = p1; p1 = p2; p2 = tmp;
    }

    // ---- epilogue: per-row top-2 within this block's 256 cols ----
    __syncthreads();
    unsigned long long* mb = (unsigned long long*)smem;  // [256][4][4][2] 64KB
    float es_j[4];
    #pragma unroll
    for (int j = 0; j < 4; ++j)
        es_j[j] = esf[by * 256 + wn * 64 + j * 16 + lr];

    #pragma unroll
    for (int i = 0; i < 8; ++i) {
        #pragma unroll
        for (int r = 0; r < 4; ++r) {
            unsigned long long k1 = ~0ull, k2 = ~0ull;
            #pragma unroll
            for (int j = 0; j < 4; ++j) {
                float v = fmaf(-2.f, acc[i][j][r], es_j[j]);
                int col = by * 256 + wn * 64 + j * 16 + lr;
                unsigned long long k =
                    ((unsigned long long)fkey(v) << 32) | (unsigned)col;
                if (k < k1) { k2 = k1; k1 = k; }
                else if (k < k2) { k2 = k; }
            }
            #pragma unroll
            for (int m = 1; m <= 2; m <<= 1) {
                unsigned long long o1 = shflxor_u64(k1, m);
                unsigned long long o2 = shflxor_u64(k2, m);
                unsigned long long n1 = k1 < o1 ? k1 : o1;
                unsigned long long hi = k1 < o1 ? o1 : k1;
                unsigned long long l2 = k2 < o2 ? k2 : o2;
                k1 = n1;
                k2 = hi < l2 ? hi : l2;
            }
            if ((lr & 3) == 0) {
                int row = wm * 128 + i * 16 + lg * 4 + r;
                int idx = (row * 32 + wn * 8 + (lr >> 2) * 2);
                mb[idx + 0] = k1;
                mb[idx + 1] = k2;
            }
        }
    }
    __syncthreads();

    if (t < 256) {
        unsigned long long k1 = ~0ull, k2 = ~0ull;
        #pragma unroll 4
        for (int q = 0; q < 32; ++q) {
            unsigned long long k = mb[t * 32 + q];
            if (k < k1) { k2 = k1; k1 = k; }
            else if (k < k2) { k2 = k; }
        }
        size_t o = ((size_t)(bx * 256 + t) * 32 + by) * 2;
        tab[o + 0] = k1;
        tab[o + 1] = k2;
    }
}

// ---------------------------------------------------------------------------
// K2: collect candidates within DELTA of each row's approx min.
// Also inits rowkey (=inf; every row has >=1 candidate so rescore fills it)
// and zeroes counts (replaces two hipMemsetAsync dispatches).
// ---------------------------------------------------------------------------
__global__ __launch_bounds__(256)
void collect_kernel(const unsigned long long* __restrict__ tab,
                    unsigned* __restrict__ cand, int* __restrict__ ncand,
                    unsigned long long* __restrict__ rowkey,
                    int* __restrict__ counts)
{
    int t = threadIdx.x, lane = t & 63;
    if (blockIdx.x < 32) counts[blockIdx.x * 256 + t] = 0;
    int row = blockIdx.x * 4 + (t >> 6);
    unsigned long long k = tab[(size_t)row * 64 + lane];
    unsigned long long m = k;
    #pragma unroll
    for (int mask = 1; mask <= 32; mask <<= 1) {
        unsigned long long o = shflxor_u64(m, mask);
        m = o < m ? o : m;
    }
    if (lane == 0) rowkey[row] = ~0ull;
    float vb = unfkey((unsigned)(m >> 32));
    unsigned uthr = fkey(vb + DELTA);
    if ((unsigned)(k >> 32) <= uthr) {
        int pos = atomicAdd(ncand, 1);
        if (pos < CAP)
            cand[pos] = ((unsigned)row << 13) | (unsigned)(k & 8191u);
    }
}

// ---------------------------------------------------------------------------
// K3: exact fp32 rescore of candidates -> atomicMin final row keys.
// ---------------------------------------------------------------------------
__global__ __launch_bounds__(256)
void rescore_kernel(const float* __restrict__ z, const float* __restrict__ emb,
                    const float* __restrict__ esf,
                    const unsigned* __restrict__ cand,
                    const int* __restrict__ ncand,
                    unsigned long long* __restrict__ rowkey)
{
    int n = *ncand; if (n > CAP) n = CAP;
    int wid = blockIdx.x * 4 + (threadIdx.x >> 6);
    int lane = threadIdx.x & 63;
    for (int c = wid; c < n; c += 4096) {
        unsigned pc = cand[c];
        int row = pc >> 13, col = pc & 8191;
        const float4* zr = (const float4*)(z + (size_t)row * DIMS + lane * 8);
        const float4* er = (const float4*)(emb + (size_t)col * DIMS + lane * 8);
        float4 a0 = zr[0], a1 = zr[1], b0 = er[0], b1 = er[1];
        float s = a0.x * b0.x;
        s = fmaf(a0.y, b0.y, s); s = fmaf(a0.z, b0.z, s);
        s = fmaf(a0.w, b0.w, s); s = fmaf(a1.x, b1.x, s);
        s = fmaf(a1.y, b1.y, s); s = fmaf(a1.z, b1.z, s);
        s = fmaf(a1.w, b1.w, s);
        #pragma unroll
        for (int mask = 32; mask; mask >>= 1) s += __shfl_xor(s, mask);
        if (lane == 0) {
            float v = fmaf(-2.f, s, esf[col]);
            unsigned long long key =
                ((unsigned long long)fkey(v) << 32) | (unsigned)col;
            atomicMin(rowkey + row, key);
        }
    }
}

// ---------------------------------------------------------------------------
// K4: gather + loss partials + index output + histogram.
// ---------------------------------------------------------------------------
__global__ __launch_bounds__(256)
void gather_loss_kernel(const float* __restrict__ z, const float* __restrict__ emb,
                        const unsigned long long* __restrict__ rowkey,
                        float* __restrict__ outq, float* __restrict__ out_idx_f,
                        int* __restrict__ counts, float* __restrict__ bsums)
{
    int gid = blockIdx.x * 256 + threadIdx.x;
    int row = gid >> 7;
    int c4  = (gid & 127) << 2;
    int idx = (int)(rowkey[row] & 0xFFFFFFFFull);
    if ((gid & 127) == 0) {
        out_idx_f[row] = (float)idx;
        atomicAdd(&counts[idx], 1);
    }
    float4 e  = *(const float4*)&emb[(size_t)idx * DIMS + c4];
    float4 zv = *(const float4*)&z[(size_t)row * DIMS + c4];
    *(float4*)&outq[(size_t)row * DIMS + c4] = e;
    float dx = e.x - zv.x, dy = e.y - zv.y, dz = e.z - zv.z, dw = e.w - zv.w;
    float s = dx * dx + dy * dy + dz * dz + dw * dw;
    #pragma unroll
    for (int off = 32; off; off >>= 1) s += __shfl_down(s, off);
    __shared__ float wsum[4];
    if ((threadIdx.x & 63) == 0) wsum[threadIdx.x >> 6] = s;
    __syncthreads();
    if (threadIdx.x == 0)
        bsums[blockIdx.x] = wsum[0] + wsum[1] + wsum[2] + wsum[3];
}

// ---------------------------------------------------------------------------
// K5: finalize scalars: vq_loss and perplexity
// ---------------------------------------------------------------------------
__global__ __launch_bounds__(256)
void finalize_kernel(const int* __restrict__ counts, const float* __restrict__ bsums,
                     float* __restrict__ out_scalars)
{
    int t = threadIdx.x;
    double ls = 0.0, ps = 0.0;
    for (int i = t; i < 8192; i += 256) {
        ls += (double)bsums[i];
        double avg = (double)counts[i] * (1.0 / 16384.0);
        ps += avg * log(avg + 1e-10);
    }
    #pragma unroll
    for (int off = 32; off; off >>= 1) {
        ls += __shfl_down(ls, off);
        ps += __shfl_down(ps, off);
    }
    __shared__ double l4[4], p4[4];
    if ((t & 63) == 0) { l4[t >> 6] = ls; p4[t >> 6] = ps; }
    __syncthreads();
    if (t == 0) {
        double L = l4[0] + l4[1] + l4[2] + l4[3];
        double P = p4[0] + p4[1] + p4[2] + p4[3];
        out_scalars[0] = (float)(1.25 * L / 8388608.0);
        out_scalars[1] = (float)exp(-P);
    }
}

// ---------------------------------------------------------------------------
// ws layout (bytes):
//   rowkey u64[16384] @ 0       (131072)  (init by collect)
//   counts int[8192]  @ 131072  (32768)   (zeroed by collect)
//   ncand  int        @ 163840  (4)       (zeroed by prep)
//   bsums  f32[8192]  @ 164096  (32768)
//   esf    f32[8192]  @ 196864  (32768)
//   cand   u32[CAP]   @ 229632  (1048576)
// d_out scratch reuse (consumed before gather overwrites):
//   zh16 @ 0 (16MB) | eh16 @ 16777216 (8MB) | tab @ 25165824 (8MB)
// d_out final (floats): quantized[8388608] | vq_loss | perplexity | idx[16384]
// ---------------------------------------------------------------------------
extern "C" void kernel_launch(void* const* d_in, const int* in_sizes, int n_in,
                              void* d_out, int out_size, void* d_ws, size_t ws_size,
                              hipStream_t stream)
{
    const float* z   = (const float*)d_in[0];
    const float* emb = (const float*)d_in[1];

    float* out         = (float*)d_out;
    float* outq        = out;
    float* out_scalars = out + 8388608;
    float* out_idx     = out + 8388610;

    char* ob = (char*)d_out;
    _Float16* zh16 = (_Float16*)(ob + 0);
    _Float16* eh16 = (_Float16*)(ob + 16777216);
    unsigned long long* tab = (unsigned long long*)(ob + 25165824);

    char* ws = (char*)d_ws;
    unsigned long long* rowkey = (unsigned long long*)(ws + 0);
    int*      counts = (int*)     (ws + 131072);
    int*      ncand  = (int*)     (ws + 163840);
    float*    bsums  = (float*)   (ws + 164096);
    float*    esf    = (float*)   (ws + 196864);
    unsigned* cand   = (unsigned*)(ws + 229632);

    prep_kernel<<<3584, 256, 0, stream>>>(z, emb, zh16, eh16, esf, ncand);
    screen_kernel<<<dim3(64, 32), 512, 0, stream>>>((const char*)zh16,
                                                    (const char*)eh16, esf, tab);
    collect_kernel<<<4096, 256, 0, stream>>>(tab, cand, ncand, rowkey, counts);
    rescore_kernel<<<1024, 256, 0, stream>>>(z, emb, esf, cand, ncand, rowkey);
    gather_loss_kernel<<<8192, 256, 0, stream>>>(z, emb, rowkey, outq, out_idx,
                                                 counts, bsums);
    finalize_kernel<<<1, 256, 0, stream>>>(counts, bsums, out_scalars);
}